// Round 18
// baseline (197.656 us; speedup 1.0000x reference)
//
#include <hip/hip_runtime.h>
#include <hip/hip_bf16.h>
#include <cstdint>
#include <cstddef>

using bf16 = __hip_bfloat16;
typedef __attribute__((ext_vector_type(8))) short short8;
typedef __attribute__((ext_vector_type(4))) float f32x4;
typedef __attribute__((ext_vector_type(2))) int i32x2;

#define DEV static __device__ __forceinline__

// B=2, S=2048, D=768, H=12, DK=64, HID=3072, M = B*S = 4096
#define MROWS 4096
#define SEQ   2048
#define DMODEL 768
#define NHEAD 12
#define DHEAD 64
#define HID   3072
// 0.125 * log2(e): QK^T lands in exp2 domain
#define QSCALE 0.1803368801111204f

DEV void gload16(const void* g, void* l) {
  __builtin_amdgcn_global_load_lds((const __attribute__((address_space(1))) void*)g,
                                   (__attribute__((address_space(3))) void*)l, 16, 0, 0);
}

template <int CTRL>
DEV float dppf(float x) {
  return __builtin_bit_cast(float,
      __builtin_amdgcn_mov_dpp(__builtin_bit_cast(int, x), CTRL, 0xF, 0xF, true));
}
DEV float red_add16(float x) {
  x += dppf<0xB1>(x);
  x += dppf<0x4E>(x);
  x += dppf<0x141>(x);
  x += dppf<0x140>(x);
  return x;
}

// Branch-free exact-GELU via Abramowitz-Stegun 7.1.26 erf (|eps|<1.5e-7).
DEV float gelu_exact(float x) {
  float z = fabsf(x) * 0.70710678118f;
  float t = __builtin_amdgcn_rcpf(fmaf(0.3275911f, z, 1.0f));
  float poly = fmaf(1.061405429f, t, -1.453152027f);
  poly = fmaf(poly, t, 1.421413741f);
  poly = fmaf(poly, t, -0.284496736f);
  poly = fmaf(poly, t, 0.254829592f);
  poly *= t;
  float e = __builtin_amdgcn_exp2f(-0.72134752044f * x * x);  // exp(-z^2)
  float erfv = fmaf(-poly, e, 1.0f);
  erfv = copysignf(erfv, x);
  return 0.5f * x * (1.0f + erfv);
}

// ---------------- coalesced transpose-convert: fp32 [R][C] -> bf16 [C][R] ----------------
__global__ __launch_bounds__(256) void tcvt_k(const float* __restrict__ in,
                                              bf16* __restrict__ out, int R, int C) {
  __shared__ float tile[64][65];
  const int r0 = blockIdx.y * 64, c0 = blockIdx.x * 64;
  const int tid = threadIdx.x, lr = tid & 63, lw = tid >> 6;
#pragma unroll
  for (int i = 0; i < 16; ++i) {
    int r = i * 4 + lw;
    tile[r][lr] = in[(size_t)(r0 + r) * C + c0 + lr];
  }
  __syncthreads();
#pragma unroll
  for (int i = 0; i < 16; ++i) {
    int c = i * 4 + lw;
    out[(size_t)(c0 + c) * R + r0 + lr] = __float2bfloat16(tile[lr][c]);
  }
}

// Per-(proj,head) transpose [768][64] -> [64][768] into WqkvT rows proj*768+h*64.
__global__ __launch_bounds__(256) void tcvt_qkv_k(const float* __restrict__ Wq,
                                                  const float* __restrict__ Wk,
                                                  const float* __restrict__ Wv,
                                                  bf16* __restrict__ out) {
  __shared__ float tile[64][65];
  const int z = blockIdx.z;                 // proj*12 + hh
  const int proj = z / 12, hh = z - proj * 12;
  const float* W = (proj == 0 ? Wq : (proj == 1 ? Wk : Wv)) + (size_t)hh * DMODEL * DHEAD;
  bf16* o = out + (size_t)(proj * DMODEL + hh * DHEAD) * DMODEL;
  const int r0 = blockIdx.y * 64;
  const int tid = threadIdx.x, lr = tid & 63, lw = tid >> 6;
#pragma unroll
  for (int i = 0; i < 16; ++i) {
    int r = i * 4 + lw;
    tile[r][lr] = W[(size_t)(r0 + r) * DHEAD + lr];
  }
  __syncthreads();
#pragma unroll
  for (int i = 0; i < 16; ++i) {
    int c = i * 4 + lw;
    o[(size_t)c * DMODEL + r0 + lr] = __float2bfloat16(tile[lr][c]);
  }
}

// ---------------- layernorm (row of 768) ----------------
__global__ __launch_bounds__(256) void ln_k(const float* __restrict__ in,
                                            const float* __restrict__ gam,
                                            const float* __restrict__ bet,
                                            bf16* __restrict__ out) {
  int r = blockIdx.x;
  int tid = threadIdx.x;
  const float* p = in + (size_t)r * DMODEL;
  float v0 = p[tid], v1 = p[tid + 256], v2 = p[tid + 512];
  float s = v0 + v1 + v2;
  float ss = v0 * v0 + v1 * v1 + v2 * v2;
#pragma unroll
  for (int off = 1; off < 64; off <<= 1) {
    s += __shfl_xor(s, off);
    ss += __shfl_xor(ss, off);
  }
  __shared__ float rs[4], rss[4];
  int w = tid >> 6, l = tid & 63;
  if (l == 0) { rs[w] = s; rss[w] = ss; }
  __syncthreads();
  s = rs[0] + rs[1] + rs[2] + rs[3];
  ss = rss[0] + rss[1] + rss[2] + rss[3];
  float mean = s * (1.0f / 768.0f);
  float var = ss * (1.0f / 768.0f) - mean * mean;
  float inv = rsqrtf(var + 1e-5f);
  bf16* o = out + (size_t)r * DMODEL;
  o[tid]       = __float2bfloat16((v0 - mean) * inv * gam[tid] + bet[tid]);
  o[tid + 256] = __float2bfloat16((v1 - mean) * inv * gam[tid + 256] + bet[tid + 256]);
  o[tid + 512] = __float2bfloat16((v2 - mean) * inv * gam[tid + 512] + bet[tid + 512]);
}

// ---------------- shared epilogue ----------------
template <int EPI>
DEV void gemm_epilogue(int r, int c, float v,
                       bf16* __restrict__ ob, float* __restrict__ of,
                       const float* __restrict__ add, const float* __restrict__ bias,
                       bf16* __restrict__ vt) {
  if constexpr (EPI == 0) {
    if (c < 1536) {
      float scv = (c < DMODEL) ? QSCALE : 1.0f;  // Q pre-scaled into exp2 domain
      ob[(size_t)r * 1536 + c] = __float2bfloat16(v * scv);
    } else {
      int within = c - 1536;
      int hh = within >> 6, kk = within & 63;
      int bidx = r >> 11, sq = r & 2047;
      int sqp = (sq & ~63) | ((sq & 15) << 2) | ((sq >> 4) & 3);  // V key-permute
      vt[(((size_t)bidx * NHEAD + hh) * DHEAD + kk) * SEQ + sqp] = __float2bfloat16(v);
    }
  } else if constexpr (EPI == 1) {
    of[(size_t)r * DMODEL + c] = add[(size_t)r * DMODEL + c] + v;
  } else if constexpr (EPI == 2) {
    ob[(size_t)r * HID + c] = __float2bfloat16(gelu_exact(v + bias[c]));
  } else {
    of[(size_t)r * DMODEL + c] = add[(size_t)r * DMODEL + c] + v + bias[c];
  }
}

// ---------------- GEMM64: 64x64 tile, BK=64, TRIPLE-buffer (2-iteration load flight) ----------------
// {vmcnt(4): tile t landed (t+1's 4 loads may fly) ; barrier ; stage(t+2) ;
//  ds_read(t)+MFMA}. Tile t's loads issued at t-2 -> TWO iterations of flight,
// decoupling iteration time from L2/L3 latency. WAR: stage(t+2) writes
// buf[(t-1)%3]; all its readers passed this iteration's barrier.
template <int EPI>
__global__ __launch_bounds__(256) void gemm64_bt(const bf16* __restrict__ A,
                                                 const bf16* __restrict__ Bt, int K,
                                                 bf16* __restrict__ ob,
                                                 float* __restrict__ of,
                                                 const float* __restrict__ add,
                                                 const float* __restrict__ bias,
                                                 bf16* __restrict__ vt) {
  __shared__ bf16 sA[3][64 * 64];
  __shared__ bf16 sB[3][64 * 64];
  const int tid = threadIdx.x;
  const int w = tid >> 6, l = tid & 63;
  const int lr = l & 15, lg = l >> 4;
  const int mbase = blockIdx.y * 64, nbase = blockIdx.x * 64;
  const int wm = (w >> 1) * 32, wn = (w & 1) * 32;

  f32x4 acc[2][2];
#pragma unroll
  for (int i = 0; i < 2; ++i)
#pragma unroll
    for (int j = 0; j < 2; ++j) acc[i][j] = (f32x4)0.0f;

  const int srow3 = l >> 3;
  const int csrc = ((l & 7) ^ srow3) * 8;
  const bf16* gA = A + (size_t)(mbase + w * 16 + srow3) * K + csrc;
  const bf16* gB = Bt + (size_t)(nbase + w * 16 + srow3) * K + csrc;

  int rowa[2], rowb[2], cswz[2];
#pragma unroll
  for (int mi = 0; mi < 2; ++mi) rowa[mi] = (wm + mi * 16 + lr) * 64;
#pragma unroll
  for (int ni = 0; ni < 2; ++ni) rowb[ni] = (wn + ni * 16 + lr) * 64;
#pragma unroll
  for (int kk = 0; kk < 2; ++kk) cswz[kk] = (((kk * 4 + lg) ^ (lr & 7)) << 3);

#define GSTAGE64(bufi, t)                                                    \
  {                                                                          \
    const int k0_ = (t) * 64;                                                \
    gload16(gA + k0_,                 &sA[bufi][(w * 16) * 64]);             \
    gload16(gA + k0_ + (size_t)8 * K, &sA[bufi][(w * 16 + 8) * 64]);         \
    gload16(gB + k0_,                 &sB[bufi][(w * 16) * 64]);             \
    gload16(gB + k0_ + (size_t)8 * K, &sB[bufi][(w * 16 + 8) * 64]);         \
  }

  const int nt = K >> 6;
  GSTAGE64(0, 0);
  GSTAGE64(1, 1);
  int cur = 0;
  for (int t = 0; t < nt; ++t) {
    if (t + 1 < nt) {
      asm volatile("s_waitcnt vmcnt(4)" ::: "memory");   // tile t landed; t+1 flying
    } else {
      asm volatile("s_waitcnt vmcnt(0)" ::: "memory");
    }
    __builtin_amdgcn_s_barrier();          // tile t ready; buf[(t+2)%3] readers done

    if (t + 2 < nt) {
      int stg = cur + 2; if (stg >= 3) stg -= 3;
      GSTAGE64(stg, t + 2);
    }

    short8 a[2][2], bb[2][2];
#pragma unroll
    for (int mi = 0; mi < 2; ++mi)
#pragma unroll
      for (int kk = 0; kk < 2; ++kk)
        a[mi][kk] = *(const short8*)&sA[cur][rowa[mi] + cswz[kk]];
#pragma unroll
    for (int ni = 0; ni < 2; ++ni)
#pragma unroll
      for (int kk = 0; kk < 2; ++kk)
        bb[ni][kk] = *(const short8*)&sB[cur][rowb[ni] + cswz[kk]];
#pragma unroll
    for (int mi = 0; mi < 2; ++mi)
#pragma unroll
      for (int ni = 0; ni < 2; ++ni) {
        acc[mi][ni] = __builtin_amdgcn_mfma_f32_16x16x32_bf16(a[mi][0], bb[ni][0], acc[mi][ni], 0, 0, 0);
        acc[mi][ni] = __builtin_amdgcn_mfma_f32_16x16x32_bf16(a[mi][1], bb[ni][1], acc[mi][ni], 0, 0, 0);
      }

    cur = (cur == 2) ? 0 : cur + 1;
  }
#undef GSTAGE64

  const int row0 = mbase + wm + lg * 4;
  const int col0 = nbase + wn + lr;
#pragma unroll
  for (int mi = 0; mi < 2; ++mi)
#pragma unroll
    for (int ni = 0; ni < 2; ++ni)
#pragma unroll
      for (int i = 0; i < 4; ++i)
        gemm_epilogue<EPI>(row0 + mi * 16 + i, col0 + ni * 16, acc[mi][ni][i],
                           ob, of, add, bias, vt);
}

// ---------------- flash attention (causal), v8: split-K (round-13 proven) ----------------
__global__ __launch_bounds__(256) void attn_k(const bf16* __restrict__ qk,
                                              const bf16* __restrict__ vt,
                                              bf16* __restrict__ o,
                                              float* __restrict__ opart,
                                              float* __restrict__ lpart) {
  __shared__ bf16 sK[2][64 * 64];
  __shared__ bf16 sV[2][64 * 64];
  __shared__ bf16 sP[64 * 64];

  const int d = blockIdx.x;                 // 0..1919
  const int bh = d % 24;
  const int rank = d / 24;                  // 0..79
  const int j = 79 - rank;                  // LPT: fattest chunks dispatch first
  int qt, chunk, nch;
  if (j < 8)       { qt = j;                        chunk = 0;           nch = 1; }
  else if (j < 24) { int r_ = j - 8;  qt = 8  + (r_ >> 1); chunk = r_ & 1;  nch = 2; }
  else if (j < 48) { int r_ = j - 24; qt = 16 + r_ / 3;    chunk = r_ % 3;  nch = 3; }
  else             { int r_ = j - 48; qt = 24 + (r_ >> 2); chunk = r_ & 3;  nch = 4; }
  const int nt_q = qt + 1;
  const int t0 = (chunk * nt_q) / nch;
  const int t1 = ((chunk + 1) * nt_q) / nch;

  const int b = bh / NHEAD, h = bh - b * NHEAD;
  const int qbase = qt * 64;
  const int tid = threadIdx.x, w = tid >> 6, l = tid & 63;
  const int lr = l & 15, lg = l >> 4;

  short8 q[2];
#pragma unroll
  for (int kk = 0; kk < 2; ++kk)
    q[kk] = *(const short8*)&qk[(size_t)(b * SEQ + qbase + w * 16 + lr) * 1536 + h * DHEAD + kk * 32 + lg * 8];

  f32x4 oa[4];
  float lst[4];
#pragma unroll
  for (int i = 0; i < 4; ++i) { oa[i] = (f32x4)0.0f; lst[i] = 0.0f; }

  const int srow3 = l >> 3;
  const int csrc = (l & 7) ^ srow3;
  const bf16* gKb = qk + ((size_t)(b * SEQ) + w * 16 + srow3) * 1536 + DMODEL + h * DHEAD + csrc * 8;
  const bf16* gVb = vt + ((size_t)bh * DHEAD + w * 16 + srow3) * SEQ + csrc * 8;

  int rowb[4], cswz[2];
#pragma unroll
  for (int ni = 0; ni < 4; ++ni) rowb[ni] = (ni * 16 + lr) * 64;
#pragma unroll
  for (int kk = 0; kk < 2; ++kk) cswz[kk] = (((kk * 4 + lg) ^ (lr & 7)) << 3);
  const int prow = (w * 16 + lr) * 64;

#define STAGE(buf, t)                                                              \
  {                                                                                \
    const int kb_ = (t) * 64;                                                      \
    gload16(gKb + (size_t)kb_ * 1536,        &sK[buf][(w * 16) * 64]);             \
    gload16(gKb + (size_t)(kb_ + 8) * 1536,  &sK[buf][(w * 16 + 8) * 64]);         \
    gload16(gVb + kb_,                       &sV[buf][(w * 16) * 64]);             \
    gload16(gVb + kb_ + (size_t)8 * SEQ,     &sV[buf][(w * 16 + 8) * 64]);         \
  }

  STAGE(0, t0);

  for (int t = t0; t < t1; ++t) {
    const int cur = (t - t0) & 1;
    const int kb = t * 64;
    if (t + 1 < t1) {
      STAGE(cur ^ 1, t + 1);
      asm volatile("s_waitcnt vmcnt(4)" ::: "memory");
    } else {
      asm volatile("s_waitcnt vmcnt(0)" ::: "memory");
    }
    __builtin_amdgcn_s_barrier();

    const bf16* sKc = sK[cur];
    const bf16* sVc = sV[cur];

    f32x4 sc[4];
    __builtin_amdgcn_s_setprio(1);
#pragma unroll
    for (int ni = 0; ni < 4; ++ni) {
      sc[ni] = (f32x4)0.0f;
#pragma unroll
      for (int kk = 0; kk < 2; ++kk) {
        short8 kf = *(const short8*)&sKc[rowb[ni] + cswz[kk]];
        sc[ni] = __builtin_amdgcn_mfma_f32_16x16x32_bf16(q[kk], kf, sc[ni], 0, 0, 0);
      }
    }
    __builtin_amdgcn_s_setprio(0);

    const bool need_mask = (kb + 63) > (qbase + w * 16);
    const int qrow0 = qbase + w * 16 + lg * 4;
#pragma unroll
    for (int i = 0; i < 4; ++i) {
      float v0 = sc[0][i], v1 = sc[1][i], v2 = sc[2][i], v3 = sc[3][i];
      if (need_mask) {
        const int qg = qrow0 + i;
        v0 = (kb + lr      > qg) ? -1e30f : v0;
        v1 = (kb + 16 + lr > qg) ? -1e30f : v1;
        v2 = (kb + 32 + lr > qg) ? -1e30f : v2;
        v3 = (kb + 48 + lr > qg) ? -1e30f : v3;
      }
      float p0 = exp2f(v0), p1 = exp2f(v1), p2 = exp2f(v2), p3 = exp2f(v3);
      lst[i] += (p0 + p1) + (p2 + p3);
      int r0, r1;
      asm("v_cvt_pk_bf16_f32 %0, %1, %2" : "=v"(r0) : "v"(p0), "v"(p1));
      asm("v_cvt_pk_bf16_f32 %0, %1, %2" : "=v"(r1) : "v"(p2), "v"(p3));
      const int rrow = w * 16 + lg * 4 + i;
      *(i32x2*)((char*)sP + rrow * 128 + ((lr * 8) ^ ((rrow & 7) << 4))) = (i32x2){r0, r1};
    }

    short8 pf0 = *(const short8*)&sP[prow + cswz[0]];
    short8 pf1 = *(const short8*)&sP[prow + cswz[1]];
    __builtin_amdgcn_s_setprio(1);
#pragma unroll
    for (int nk = 0; nk < 4; ++nk) {
      short8 vf0 = *(const short8*)&sVc[rowb[nk] + cswz[0]];
      short8 vf1 = *(const short8*)&sVc[rowb[nk] + cswz[1]];
      oa[nk] = __builtin_amdgcn_mfma_f32_16x16x32_bf16(pf0, vf0, oa[nk], 0, 0, 0);
      oa[nk] = __builtin_amdgcn_mfma_f32_16x16x32_bf16(pf1, vf1, oa[nk], 0, 0, 0);
    }
    __builtin_amdgcn_s_setprio(0);
    __builtin_amdgcn_s_barrier();
  }
#undef STAGE

#pragma unroll
  for (int i = 0; i < 4; ++i) lst[i] = red_add16(lst[i]);

  if (nch == 1) {
#pragma unroll
    for (int i = 0; i < 4; ++i) {
      const float rl = __builtin_amdgcn_rcpf(lst[i]);
#pragma unroll
      for (int nk = 0; nk < 4; ++nk) {
        int row = qbase + w * 16 + lg * 4 + i;
        int col = h * DHEAD + nk * 16 + lr;
        o[(size_t)(b * SEQ + row) * DMODEL + col] = __float2bfloat16(oa[nk][i] * rl);
      }
    }
  } else {
    const int slot = bh * 80 + j;
    float* op = opart + (size_t)slot * 4096;
#pragma unroll
    for (int i = 0; i < 4; ++i) {
      const int row = w * 16 + lg * 4 + i;
#pragma unroll
      for (int nk = 0; nk < 4; ++nk)
        op[row * 64 + nk * 16 + lr] = oa[nk][i];
      if (lr == 0) lpart[slot * 64 + row] = lst[i];
    }
  }
}

// ---------------- attention split-K combine ----------------
__global__ __launch_bounds__(256) void attn_comb_k(const float* __restrict__ opart,
                                                   const float* __restrict__ lpart,
                                                   bf16* __restrict__ o) {
  const int s = blockIdx.x;            // 0..575
  const int bh = s / 24;
  const int qt = 8 + (s - bh * 24);
  const int b = bh / NHEAD, h = bh - b * NHEAD;
  const int bb = qt >> 3;              // band 1..3
  const int nch = bb + 1;
  const int S0 = 4 * bb * (bb + 1) + (qt - 8 * bb) * (bb + 1);
  const int slot0 = bh * 80 + S0;

  const int tid = threadIdx.x;
  const int row = tid >> 2;            // 0..63
  const int c0 = (tid & 3) * 16;       // col group of 16

  f32x4 acc[4];
#pragma unroll
  for (int e = 0; e < 4; ++e) acc[e] = (f32x4)0.0f;
  float lsum = 0.0f;
  for (int c = 0; c < nch; ++c) {
    const f32x4* op = (const f32x4*)(opart + (size_t)(slot0 + c) * 4096 + row * 64 + c0);
    lsum += lpart[(slot0 + c) * 64 + row];
#pragma unroll
    for (int e = 0; e < 4; ++e) acc[e] += op[e];
  }
  const float rl = 1.0f / lsum;
  bf16* po = o + (size_t)(b * SEQ + qt * 64 + row) * DMODEL + h * DHEAD + c0;
#pragma unroll
  for (int e = 0; e < 4; ++e)
#pragma unroll
    for (int k = 0; k < 4; ++k)
      po[e * 4 + k] = __float2bfloat16(acc[e][k] * rl);
}

// ---------------- launch ----------------
extern "C" void kernel_launch(void* const* d_in, const int* in_sizes, int n_in,
                              void* d_out, int out_size, void* d_ws, size_t ws_size,
                              hipStream_t stream) {
  (void)in_sizes; (void)n_in; (void)out_size; (void)ws_size;
  const float* x   = (const float*)d_in[0];
  const float* Wq  = (const float*)d_in[1];
  const float* Wk  = (const float*)d_in[2];
  const float* Wv  = (const float*)d_in[3];
  const float* Wo  = (const float*)d_in[4];
  const float* W1  = (const float*)d_in[5];
  const float* b1  = (const float*)d_in[6];
  const float* W2  = (const float*)d_in[7];
  const float* b2  = (const float*)d_in[8];
  const float* g1  = (const float*)d_in[9];
  const float* be1 = (const float*)d_in[10];
  const float* g2  = (const float*)d_in[11];
  const float* be2 = (const float*)d_in[12];
  float* out = (float*)d_out;

  char* p = (char*)d_ws;
  bf16* WqkvT = (bf16*)p; p += (size_t)2304 * 768 * 2;
  bf16* WoT   = (bf16*)p; p += (size_t)768 * 768 * 2;
  bf16* W1T   = (bf16*)p; p += (size_t)3072 * 768 * 2;
  bf16* W2T   = (bf16*)p; p += (size_t)768 * 3072 * 2;
  bf16* h1    = (bf16*)p; p += (size_t)MROWS * DMODEL * 2;
  char* alias0 = p;                                   // U aliases QK+Vt+O (dead by then)
  bf16* QK    = (bf16*)p; p += (size_t)MROWS * 1536 * 2;
  bf16* Vt    = (bf16*)p; p += (size_t)24 * DHEAD * SEQ * 2;
  bf16* O     = (bf16*)p; p += (size_t)MROWS * DMODEL * 2;
  float* y    = (float*)p; p += (size_t)MROWS * DMODEL * 4;
  bf16* h2    = (bf16*)p; p += (size_t)MROWS * DMODEL * 2;
  float* Opart = (float*)p; p += (size_t)24 * 80 * 4096 * 4;   // 31.5 MB
  float* Lpart = (float*)p; p += (size_t)24 * 80 * 64 * 4;     // 0.5 MB
  bf16* U     = (bf16*)alias0;                        // [4096][3072] bf16

  dim3 blk(256);
  tcvt_qkv_k<<<dim3(1, 12, 36), blk, 0, stream>>>(Wq, Wk, Wv, WqkvT);
  tcvt_k<<<dim3(12, 12), blk, 0, stream>>>(Wo, WoT, 768, 768);
  tcvt_k<<<dim3(48, 12), blk, 0, stream>>>(W1, W1T, 768, 3072);
  tcvt_k<<<dim3(12, 48), blk, 0, stream>>>(W2, W2T, 3072, 768);
  ln_k<<<MROWS, blk, 0, stream>>>(x, g1, be1, h1);
  gemm64_bt<0><<<dim3(36, 64), blk, 0, stream>>>(h1, WqkvT, 768, QK, nullptr, nullptr, nullptr, Vt);
  attn_k<<<1920, blk, 0, stream>>>(QK, Vt, O, Opart, Lpart);
  attn_comb_k<<<576, blk, 0, stream>>>(Opart, Lpart, O);
  gemm64_bt<1><<<dim3(12, 64), blk, 0, stream>>>(O, WoT, 768, nullptr, y, x, nullptr, nullptr);
  ln_k<<<MROWS, blk, 0, stream>>>(y, g2, be2, h2);
  gemm64_bt<2><<<dim3(48, 64), blk, 0, stream>>>(h2, W1T, 768, U, nullptr, nullptr, b1, nullptr);
  gemm64_bt<3><<<dim3(12, 64), blk, 0, stream>>>(U, W2T, 3072, nullptr, out, y, b2, nullptr);
}

// Round 19
// 181.298 us; speedup vs baseline: 1.0902x; 1.0902x over previous
//
#include <hip/hip_runtime.h>
#include <hip/hip_bf16.h>
#include <cstdint>
#include <cstddef>

using bf16 = __hip_bfloat16;
typedef __attribute__((ext_vector_type(8))) short short8;
typedef __attribute__((ext_vector_type(4))) float f32x4;
typedef __attribute__((ext_vector_type(2))) int i32x2;

#define DEV static __device__ __forceinline__

// B=2, S=2048, D=768, H=12, DK=64, HID=3072, M = B*S = 4096
#define MROWS 4096
#define SEQ   2048
#define DMODEL 768
#define NHEAD 12
#define DHEAD 64
#define HID   3072
// 0.125 * log2(e): QK^T lands in exp2 domain
#define QSCALE 0.1803368801111204f

DEV void gload16(const void* g, void* l) {
  __builtin_amdgcn_global_load_lds((const __attribute__((address_space(1))) void*)g,
                                   (__attribute__((address_space(3))) void*)l, 16, 0, 0);
}

template <int CTRL>
DEV float dppf(float x) {
  return __builtin_bit_cast(float,
      __builtin_amdgcn_mov_dpp(__builtin_bit_cast(int, x), CTRL, 0xF, 0xF, true));
}
DEV float red_add16(float x) {
  x += dppf<0xB1>(x);
  x += dppf<0x4E>(x);
  x += dppf<0x141>(x);
  x += dppf<0x140>(x);
  return x;
}

// Branch-free exact-GELU via Abramowitz-Stegun 7.1.26 erf (|eps|<1.5e-7).
DEV float gelu_exact(float x) {
  float z = fabsf(x) * 0.70710678118f;
  float t = __builtin_amdgcn_rcpf(fmaf(0.3275911f, z, 1.0f));
  float poly = fmaf(1.061405429f, t, -1.453152027f);
  poly = fmaf(poly, t, 1.421413741f);
  poly = fmaf(poly, t, -0.284496736f);
  poly = fmaf(poly, t, 0.254829592f);
  poly *= t;
  float e = __builtin_amdgcn_exp2f(-0.72134752044f * x * x);  // exp(-z^2)
  float erfv = fmaf(-poly, e, 1.0f);
  erfv = copysignf(erfv, x);
  return 0.5f * x * (1.0f + erfv);
}

// ---------------- merged weight prep: all 4 transposes in ONE launch ----------------
// blocks [0,432): Wq/Wk/Wv per-head transpose -> WqkvT
// blocks [432,576): Wo 768x768 ; [576,1152): W1 768x3072 ; [1152,1728): W2 3072x768
__global__ __launch_bounds__(256) void prep_k(const float* __restrict__ Wq,
                                              const float* __restrict__ Wk,
                                              const float* __restrict__ Wv,
                                              const float* __restrict__ Wo,
                                              const float* __restrict__ W1,
                                              const float* __restrict__ W2,
                                              bf16* __restrict__ WqkvT,
                                              bf16* __restrict__ WoT,
                                              bf16* __restrict__ W1T,
                                              bf16* __restrict__ W2T) {
  __shared__ float tile[64][65];
  const int id = blockIdx.x;
  const int tid = threadIdx.x, lr = tid & 63, lw = tid >> 6;

  const float* in;
  bf16* out;
  int R, C, r0, c0;
  size_t ostr;          // output row stride
  if (id < 432) {
    const int y = id % 12, z = id / 12;
    const int proj = z / 12, hh = z - proj * 12;
    in = (proj == 0 ? Wq : (proj == 1 ? Wk : Wv)) + (size_t)hh * DMODEL * DHEAD;
    out = WqkvT + (size_t)(proj * DMODEL + hh * DHEAD) * DMODEL;
    R = DMODEL; C = DHEAD; r0 = y * 64; c0 = 0; ostr = DMODEL;
  } else if (id < 576) {
    const int q = id - 432;
    in = Wo; out = WoT; R = 768; C = 768; r0 = (q / 12) * 64; c0 = (q % 12) * 64; ostr = R;
  } else if (id < 1152) {
    const int q = id - 576;
    in = W1; out = W1T; R = 768; C = 3072; r0 = (q / 48) * 64; c0 = (q % 48) * 64; ostr = R;
  } else {
    const int q = id - 1152;
    in = W2; out = W2T; R = 3072; C = 768; r0 = (q / 12) * 64; c0 = (q % 12) * 64; ostr = R;
  }

#pragma unroll
  for (int i = 0; i < 16; ++i) {
    int r = i * 4 + lw;
    tile[r][lr] = in[(size_t)(r0 + r) * C + c0 + lr];
  }
  __syncthreads();
#pragma unroll
  for (int i = 0; i < 16; ++i) {
    int c = i * 4 + lw;
    out[(size_t)(c0 + c) * ostr + r0 + lr] = __float2bfloat16(tile[lr][c]);
  }
}

// ---------------- layernorm (row of 768) ----------------
__global__ __launch_bounds__(256) void ln_k(const float* __restrict__ in,
                                            const float* __restrict__ gam,
                                            const float* __restrict__ bet,
                                            bf16* __restrict__ out) {
  int r = blockIdx.x;
  int tid = threadIdx.x;
  const float* p = in + (size_t)r * DMODEL;
  float v0 = p[tid], v1 = p[tid + 256], v2 = p[tid + 512];
  float s = v0 + v1 + v2;
  float ss = v0 * v0 + v1 * v1 + v2 * v2;
#pragma unroll
  for (int off = 1; off < 64; off <<= 1) {
    s += __shfl_xor(s, off);
    ss += __shfl_xor(ss, off);
  }
  __shared__ float rs[4], rss[4];
  int w = tid >> 6, l = tid & 63;
  if (l == 0) { rs[w] = s; rss[w] = ss; }
  __syncthreads();
  s = rs[0] + rs[1] + rs[2] + rs[3];
  ss = rss[0] + rss[1] + rss[2] + rss[3];
  float mean = s * (1.0f / 768.0f);
  float var = ss * (1.0f / 768.0f) - mean * mean;
  float inv = rsqrtf(var + 1e-5f);
  bf16* o = out + (size_t)r * DMODEL;
  o[tid]       = __float2bfloat16((v0 - mean) * inv * gam[tid] + bet[tid]);
  o[tid + 256] = __float2bfloat16((v1 - mean) * inv * gam[tid + 256] + bet[tid + 256]);
  o[tid + 512] = __float2bfloat16((v2 - mean) * inv * gam[tid + 512] + bet[tid + 512]);
}

// ---------------- shared epilogue ----------------
template <int EPI>
DEV void gemm_epilogue(int r, int c, float v,
                       bf16* __restrict__ ob, float* __restrict__ of,
                       const float* __restrict__ add, const float* __restrict__ bias,
                       bf16* __restrict__ vt) {
  if constexpr (EPI == 0) {
    if (c < 1536) {
      float scv = (c < DMODEL) ? QSCALE : 1.0f;  // Q pre-scaled into exp2 domain
      ob[(size_t)r * 1536 + c] = __float2bfloat16(v * scv);
    } else {
      int within = c - 1536;
      int hh = within >> 6, kk = within & 63;
      int bidx = r >> 11, sq = r & 2047;
      int sqp = (sq & ~63) | ((sq & 15) << 2) | ((sq >> 4) & 3);  // V key-permute
      vt[(((size_t)bidx * NHEAD + hh) * DHEAD + kk) * SEQ + sqp] = __float2bfloat16(v);
    }
  } else if constexpr (EPI == 1) {
    of[(size_t)r * DMODEL + c] = add[(size_t)r * DMODEL + c] + v;
  } else if constexpr (EPI == 2) {
    ob[(size_t)r * HID + c] = __float2bfloat16(gelu_exact(v + bias[c]));
  } else {
    of[(size_t)r * DMODEL + c] = add[(size_t)r * DMODEL + c] + v + bias[c];
  }
}

// ---------------- GEMM64: 64x64 tile, BK=64, 2-buffer 2-barrier (r14 proven optimum) ----------------
// Slot ledger (r9-r18): this structure at 5 blocks/CU = ~730 cyc/iteration, the
// measured minimum across all depth/width/locality/barrier variants at these shapes.
template <int EPI>
__global__ __launch_bounds__(256) void gemm64_bt(const bf16* __restrict__ A,
                                                 const bf16* __restrict__ Bt, int K,
                                                 bf16* __restrict__ ob,
                                                 float* __restrict__ of,
                                                 const float* __restrict__ add,
                                                 const float* __restrict__ bias,
                                                 bf16* __restrict__ vt) {
  __shared__ bf16 sA[2][64 * 64];
  __shared__ bf16 sB[2][64 * 64];
  const int tid = threadIdx.x;
  const int w = tid >> 6, l = tid & 63;
  const int lr = l & 15, lg = l >> 4;
  const int mbase = blockIdx.y * 64, nbase = blockIdx.x * 64;
  const int wm = (w >> 1) * 32, wn = (w & 1) * 32;

  f32x4 acc[2][2];
#pragma unroll
  for (int i = 0; i < 2; ++i)
#pragma unroll
    for (int j = 0; j < 2; ++j) acc[i][j] = (f32x4)0.0f;

  const int srow3 = l >> 3;
  const int csrc = ((l & 7) ^ srow3) * 8;
  const bf16* gA = A + (size_t)(mbase + w * 16 + srow3) * K + csrc;
  const bf16* gB = Bt + (size_t)(nbase + w * 16 + srow3) * K + csrc;

  int rowa[2], rowb[2], cswz[2];
#pragma unroll
  for (int mi = 0; mi < 2; ++mi) rowa[mi] = (wm + mi * 16 + lr) * 64;
#pragma unroll
  for (int ni = 0; ni < 2; ++ni) rowb[ni] = (wn + ni * 16 + lr) * 64;
#pragma unroll
  for (int kk = 0; kk < 2; ++kk) cswz[kk] = (((kk * 4 + lg) ^ (lr & 7)) << 3);

#define GSTAGE64(bufi, t)                                                    \
  {                                                                          \
    const int k0_ = (t) * 64;                                                \
    gload16(gA + k0_,                 &sA[bufi][(w * 16) * 64]);             \
    gload16(gA + k0_ + (size_t)8 * K, &sA[bufi][(w * 16 + 8) * 64]);         \
    gload16(gB + k0_,                 &sB[bufi][(w * 16) * 64]);             \
    gload16(gB + k0_ + (size_t)8 * K, &sB[bufi][(w * 16 + 8) * 64]);         \
  }

  const int nt = K >> 6;
  GSTAGE64(0, 0);
  for (int t = 0; t < nt; ++t) {
    const int cur = t & 1;
    if (t + 1 < nt) {
      GSTAGE64(cur ^ 1, t + 1);
      asm volatile("s_waitcnt vmcnt(4)" ::: "memory");
    } else {
      asm volatile("s_waitcnt vmcnt(0)" ::: "memory");
    }
    __builtin_amdgcn_s_barrier();

    short8 a[2][2], bb[2][2];
#pragma unroll
    for (int mi = 0; mi < 2; ++mi)
#pragma unroll
      for (int kk = 0; kk < 2; ++kk)
        a[mi][kk] = *(const short8*)&sA[cur][rowa[mi] + cswz[kk]];
#pragma unroll
    for (int ni = 0; ni < 2; ++ni)
#pragma unroll
      for (int kk = 0; kk < 2; ++kk)
        bb[ni][kk] = *(const short8*)&sB[cur][rowb[ni] + cswz[kk]];
#pragma unroll
    for (int mi = 0; mi < 2; ++mi)
#pragma unroll
      for (int ni = 0; ni < 2; ++ni) {
        acc[mi][ni] = __builtin_amdgcn_mfma_f32_16x16x32_bf16(a[mi][0], bb[ni][0], acc[mi][ni], 0, 0, 0);
        acc[mi][ni] = __builtin_amdgcn_mfma_f32_16x16x32_bf16(a[mi][1], bb[ni][1], acc[mi][ni], 0, 0, 0);
      }

    __builtin_amdgcn_s_barrier();
  }
#undef GSTAGE64

  const int row0 = mbase + wm + lg * 4;
  const int col0 = nbase + wn + lr;
#pragma unroll
  for (int mi = 0; mi < 2; ++mi)
#pragma unroll
    for (int ni = 0; ni < 2; ++ni)
#pragma unroll
      for (int i = 0; i < 4; ++i)
        gemm_epilogue<EPI>(row0 + mi * 16 + i, col0 + ni * 16, acc[mi][ni][i],
                           ob, of, add, bias, vt);
}

// ---------------- flash attention (causal), v8: split-K (round-13 proven) ----------------
__global__ __launch_bounds__(256) void attn_k(const bf16* __restrict__ qk,
                                              const bf16* __restrict__ vt,
                                              bf16* __restrict__ o,
                                              float* __restrict__ opart,
                                              float* __restrict__ lpart) {
  __shared__ bf16 sK[2][64 * 64];
  __shared__ bf16 sV[2][64 * 64];
  __shared__ bf16 sP[64 * 64];

  const int d = blockIdx.x;                 // 0..1919
  const int bh = d % 24;
  const int rank = d / 24;                  // 0..79
  const int j = 79 - rank;                  // LPT: fattest chunks dispatch first
  int qt, chunk, nch;
  if (j < 8)       { qt = j;                        chunk = 0;           nch = 1; }
  else if (j < 24) { int r_ = j - 8;  qt = 8  + (r_ >> 1); chunk = r_ & 1;  nch = 2; }
  else if (j < 48) { int r_ = j - 24; qt = 16 + r_ / 3;    chunk = r_ % 3;  nch = 3; }
  else             { int r_ = j - 48; qt = 24 + (r_ >> 2); chunk = r_ & 3;  nch = 4; }
  const int nt_q = qt + 1;
  const int t0 = (chunk * nt_q) / nch;
  const int t1 = ((chunk + 1) * nt_q) / nch;

  const int b = bh / NHEAD, h = bh - b * NHEAD;
  const int qbase = qt * 64;
  const int tid = threadIdx.x, w = tid >> 6, l = tid & 63;
  const int lr = l & 15, lg = l >> 4;

  short8 q[2];
#pragma unroll
  for (int kk = 0; kk < 2; ++kk)
    q[kk] = *(const short8*)&qk[(size_t)(b * SEQ + qbase + w * 16 + lr) * 1536 + h * DHEAD + kk * 32 + lg * 8];

  f32x4 oa[4];
  float lst[4];
#pragma unroll
  for (int i = 0; i < 4; ++i) { oa[i] = (f32x4)0.0f; lst[i] = 0.0f; }

  const int srow3 = l >> 3;
  const int csrc = (l & 7) ^ srow3;
  const bf16* gKb = qk + ((size_t)(b * SEQ) + w * 16 + srow3) * 1536 + DMODEL + h * DHEAD + csrc * 8;
  const bf16* gVb = vt + ((size_t)bh * DHEAD + w * 16 + srow3) * SEQ + csrc * 8;

  int rowb[4], cswz[2];
#pragma unroll
  for (int ni = 0; ni < 4; ++ni) rowb[ni] = (ni * 16 + lr) * 64;
#pragma unroll
  for (int kk = 0; kk < 2; ++kk) cswz[kk] = (((kk * 4 + lg) ^ (lr & 7)) << 3);
  const int prow = (w * 16 + lr) * 64;

#define STAGE(buf, t)                                                              \
  {                                                                                \
    const int kb_ = (t) * 64;                                                      \
    gload16(gKb + (size_t)kb_ * 1536,        &sK[buf][(w * 16) * 64]);             \
    gload16(gKb + (size_t)(kb_ + 8) * 1536,  &sK[buf][(w * 16 + 8) * 64]);         \
    gload16(gVb + kb_,                       &sV[buf][(w * 16) * 64]);             \
    gload16(gVb + kb_ + (size_t)8 * SEQ,     &sV[buf][(w * 16 + 8) * 64]);         \
  }

  STAGE(0, t0);

  for (int t = t0; t < t1; ++t) {
    const int cur = (t - t0) & 1;
    const int kb = t * 64;
    if (t + 1 < t1) {
      STAGE(cur ^ 1, t + 1);
      asm volatile("s_waitcnt vmcnt(4)" ::: "memory");
    } else {
      asm volatile("s_waitcnt vmcnt(0)" ::: "memory");
    }
    __builtin_amdgcn_s_barrier();

    const bf16* sKc = sK[cur];
    const bf16* sVc = sV[cur];

    f32x4 sc[4];
    __builtin_amdgcn_s_setprio(1);
#pragma unroll
    for (int ni = 0; ni < 4; ++ni) {
      sc[ni] = (f32x4)0.0f;
#pragma unroll
      for (int kk = 0; kk < 2; ++kk) {
        short8 kf = *(const short8*)&sKc[rowb[ni] + cswz[kk]];
        sc[ni] = __builtin_amdgcn_mfma_f32_16x16x32_bf16(q[kk], kf, sc[ni], 0, 0, 0);
      }
    }
    __builtin_amdgcn_s_setprio(0);

    const bool need_mask = (kb + 63) > (qbase + w * 16);
    const int qrow0 = qbase + w * 16 + lg * 4;
#pragma unroll
    for (int i = 0; i < 4; ++i) {
      float v0 = sc[0][i], v1 = sc[1][i], v2 = sc[2][i], v3 = sc[3][i];
      if (need_mask) {
        const int qg = qrow0 + i;
        v0 = (kb + lr      > qg) ? -1e30f : v0;
        v1 = (kb + 16 + lr > qg) ? -1e30f : v1;
        v2 = (kb + 32 + lr > qg) ? -1e30f : v2;
        v3 = (kb + 48 + lr > qg) ? -1e30f : v3;
      }
      float p0 = exp2f(v0), p1 = exp2f(v1), p2 = exp2f(v2), p3 = exp2f(v3);
      lst[i] += (p0 + p1) + (p2 + p3);
      int r0, r1;
      asm("v_cvt_pk_bf16_f32 %0, %1, %2" : "=v"(r0) : "v"(p0), "v"(p1));
      asm("v_cvt_pk_bf16_f32 %0, %1, %2" : "=v"(r1) : "v"(p2), "v"(p3));
      const int rrow = w * 16 + lg * 4 + i;
      *(i32x2*)((char*)sP + rrow * 128 + ((lr * 8) ^ ((rrow & 7) << 4))) = (i32x2){r0, r1};
    }

    short8 pf0 = *(const short8*)&sP[prow + cswz[0]];
    short8 pf1 = *(const short8*)&sP[prow + cswz[1]];
    __builtin_amdgcn_s_setprio(1);
#pragma unroll
    for (int nk = 0; nk < 4; ++nk) {
      short8 vf0 = *(const short8*)&sVc[rowb[nk] + cswz[0]];
      short8 vf1 = *(const short8*)&sVc[rowb[nk] + cswz[1]];
      oa[nk] = __builtin_amdgcn_mfma_f32_16x16x32_bf16(pf0, vf0, oa[nk], 0, 0, 0);
      oa[nk] = __builtin_amdgcn_mfma_f32_16x16x32_bf16(pf1, vf1, oa[nk], 0, 0, 0);
    }
    __builtin_amdgcn_s_setprio(0);
    __builtin_amdgcn_s_barrier();
  }
#undef STAGE

#pragma unroll
  for (int i = 0; i < 4; ++i) lst[i] = red_add16(lst[i]);

  if (nch == 1) {
#pragma unroll
    for (int i = 0; i < 4; ++i) {
      const float rl = __builtin_amdgcn_rcpf(lst[i]);
#pragma unroll
      for (int nk = 0; nk < 4; ++nk) {
        int row = qbase + w * 16 + lg * 4 + i;
        int col = h * DHEAD + nk * 16 + lr;
        o[(size_t)(b * SEQ + row) * DMODEL + col] = __float2bfloat16(oa[nk][i] * rl);
      }
    }
  } else {
    const int slot = bh * 80 + j;
    float* op = opart + (size_t)slot * 4096;
#pragma unroll
    for (int i = 0; i < 4; ++i) {
      const int row = w * 16 + lg * 4 + i;
#pragma unroll
      for (int nk = 0; nk < 4; ++nk)
        op[row * 64 + nk * 16 + lr] = oa[nk][i];
      if (lr == 0) lpart[slot * 64 + row] = lst[i];
    }
  }
}

// ---------------- attention split-K combine ----------------
__global__ __launch_bounds__(256) void attn_comb_k(const float* __restrict__ opart,
                                                   const float* __restrict__ lpart,
                                                   bf16* __restrict__ o) {
  const int s = blockIdx.x;            // 0..575
  const int bh = s / 24;
  const int qt = 8 + (s - bh * 24);
  const int b = bh / NHEAD, h = bh - b * NHEAD;
  const int bb = qt >> 3;              // band 1..3
  const int nch = bb + 1;
  const int S0 = 4 * bb * (bb + 1) + (qt - 8 * bb) * (bb + 1);
  const int slot0 = bh * 80 + S0;

  const int tid = threadIdx.x;
  const int row = tid >> 2;            // 0..63
  const int c0 = (tid & 3) * 16;       // col group of 16

  f32x4 acc[4];
#pragma unroll
  for (int e = 0; e < 4; ++e) acc[e] = (f32x4)0.0f;
  float lsum = 0.0f;
  for (int c = 0; c < nch; ++c) {
    const f32x4* op = (const f32x4*)(opart + (size_t)(slot0 + c) * 4096 + row * 64 + c0);
    lsum += lpart[(slot0 + c) * 64 + row];
#pragma unroll
    for (int e = 0; e < 4; ++e) acc[e] += op[e];
  }
  const float rl = 1.0f / lsum;
  bf16* po = o + (size_t)(b * SEQ + qt * 64 + row) * DMODEL + h * DHEAD + c0;
#pragma unroll
  for (int e = 0; e < 4; ++e)
#pragma unroll
    for (int k = 0; k < 4; ++k)
      po[e * 4 + k] = __float2bfloat16(acc[e][k] * rl);
}

// ---------------- launch ----------------
extern "C" void kernel_launch(void* const* d_in, const int* in_sizes, int n_in,
                              void* d_out, int out_size, void* d_ws, size_t ws_size,
                              hipStream_t stream) {
  (void)in_sizes; (void)n_in; (void)out_size; (void)ws_size;
  const float* x   = (const float*)d_in[0];
  const float* Wq  = (const float*)d_in[1];
  const float* Wk  = (const float*)d_in[2];
  const float* Wv  = (const float*)d_in[3];
  const float* Wo  = (const float*)d_in[4];
  const float* W1  = (const float*)d_in[5];
  const float* b1  = (const float*)d_in[6];
  const float* W2  = (const float*)d_in[7];
  const float* b2  = (const float*)d_in[8];
  const float* g1  = (const float*)d_in[9];
  const float* be1 = (const float*)d_in[10];
  const float* g2  = (const float*)d_in[11];
  const float* be2 = (const float*)d_in[12];
  float* out = (float*)d_out;

  char* p = (char*)d_ws;
  bf16* WqkvT = (bf16*)p; p += (size_t)2304 * 768 * 2;
  bf16* WoT   = (bf16*)p; p += (size_t)768 * 768 * 2;
  bf16* W1T   = (bf16*)p; p += (size_t)3072 * 768 * 2;
  bf16* W2T   = (bf16*)p; p += (size_t)768 * 3072 * 2;
  bf16* h1    = (bf16*)p; p += (size_t)MROWS * DMODEL * 2;
  char* alias0 = p;                                   // U aliases QK+Vt+O (dead by then)
  bf16* QK    = (bf16*)p; p += (size_t)MROWS * 1536 * 2;
  bf16* Vt    = (bf16*)p; p += (size_t)24 * DHEAD * SEQ * 2;
  bf16* O     = (bf16*)p; p += (size_t)MROWS * DMODEL * 2;
  float* y    = (float*)p; p += (size_t)MROWS * DMODEL * 4;
  bf16* h2    = (bf16*)p; p += (size_t)MROWS * DMODEL * 2;
  float* Opart = (float*)p; p += (size_t)24 * 80 * 4096 * 4;   // 31.5 MB
  float* Lpart = (float*)p; p += (size_t)24 * 80 * 64 * 4;     // 0.5 MB
  bf16* U     = (bf16*)alias0;                        // [4096][3072] bf16

  dim3 blk(256);
  prep_k<<<1728, blk, 0, stream>>>(Wq, Wk, Wv, Wo, W1, W2, WqkvT, WoT, W1T, W2T);
  ln_k<<<MROWS, blk, 0, stream>>>(x, g1, be1, h1);
  gemm64_bt<0><<<dim3(36, 64), blk, 0, stream>>>(h1, WqkvT, 768, QK, nullptr, nullptr, nullptr, Vt);
  attn_k<<<1920, blk, 0, stream>>>(QK, Vt, O, Opart, Lpart);
  attn_comb_k<<<576, blk, 0, stream>>>(Opart, Lpart, O);
  gemm64_bt<1><<<dim3(12, 64), blk, 0, stream>>>(O, WoT, 768, nullptr, y, x, nullptr, nullptr);
  ln_k<<<MROWS, blk, 0, stream>>>(y, g2, be2, h2);
  gemm64_bt<2><<<dim3(48, 64), blk, 0, stream>>>(h2, W1T, 768, U, nullptr, nullptr, b1, nullptr);
  gemm64_bt<3><<<dim3(12, 64), blk, 0, stream>>>(U, W2T, 3072, nullptr, out, y, b2, nullptr);
}